// Round 20
// baseline (161.928 us; speedup 1.0000x reference)
//
#include <hip/hip_runtime.h>
#include <hip/hip_bf16.h>

// ---------- problem constants ----------
#define BB 8
#define TT 2048
#define EE 1024
#define SS 2000
#define HH 150
#define HP 160     // padded hidden (GEMM N)
#define KP2 192    // padded K for attn layer-2 GEMM
#define NB 640     // big-GEMM N: [a_w1 | s_w1a | s_w1b | s_w1c] -> 4 x 160
#define NT (BB*TT)     // 16384 tokens
#define NS (BB*SS)     // 16000 spans
#define SPAN_ELEMS ((long)NS*3072)

#define APLANE 520    // 64*8 + 8 ushorts
#define BPLANE 1288   // 160*8 + 8 ushorts

typedef __attribute__((ext_vector_type(8))) short short8;
typedef __attribute__((ext_vector_type(4))) float f32x4;
typedef __attribute__((ext_vector_type(4))) ushort u16x4;

__device__ __forceinline__ float b2f(ushort u) {
    union { uint i; float f; } v; v.i = ((uint)u) << 16; return v.f;
}
__device__ __forceinline__ ushort f2b(float f) {
    union { __hip_bfloat16 b; ushort u; } v; v.b = __float2bfloat16(f); return v.u;
}
__device__ __forceinline__ uint f2b2(float lo, float hi) {   // pack 2 bf16 into u32
    return (uint)f2b(lo) | ((uint)f2b(hi) << 16);
}

// ---------- weight prep (inputs verified f32) ----------
__global__ void prep_kernel(const float* __restrict__ a_w1, const float* __restrict__ s_w1,
                            const float* __restrict__ a_w2,
                            const float* __restrict__ a_b1, const float* __restrict__ a_b2,
                            const float* __restrict__ s_b1, const float* __restrict__ s_b2,
                            ushort* __restrict__ Wbig,
                            ushort* __restrict__ a_w2t,
                            float* __restrict__ biases)
{
    int j = blockIdx.x;
    int which = blockIdx.y;
    int t = threadIdx.x;
    if (which == 0) {          // j in 0..639
        int p = j / 160, jj = j - p * 160;
        for (int k = t; k < EE; k += 256) {
            float v = 0.f;
            if (jj < HH)
                v = (p == 0) ? a_w1[(long)k * HH + jj]
                             : s_w1[((long)(p - 1) * EE + k) * HH + jj];
            Wbig[(long)j * EE + k] = f2b(v);
        }
    } else if (which == 1) {
        if (j < HP)
            for (int k = t; k < KP2; k += 256)
                a_w2t[j * KP2 + k] = (j < HH && k < HH) ? f2b(a_w2[(long)k * HH + j]) : (ushort)0;
    } else {
        if (j == 0 && t < HP) {
            biases[t]          = (t < HH) ? a_b1[t] : 0.f;
            biases[HP + t]     = (t < HH) ? a_b2[t] : 0.f;
            biases[2*HP + t]   = (t < HH) ? s_b1[t] : 0.f;
            biases[3*HP + t]   = (t < HH) ? s_b2[t] : 0.f;
        }
    }
}

// ---------- big token GEMM + fused attn MLP (round-16 structure, best known) ----------
__global__ __launch_bounds__(256, 2) void big_gemm_kernel(
    const float* __restrict__ A,
    const ushort* __restrict__ Wbig,
    const float* __restrict__ biases,
    const ushort* __restrict__ a_w2t,
    const float* __restrict__ a_w3, const float* __restrict__ a_b3,
    float* __restrict__ attns, ushort* __restrict__ Pabc)
{
    __shared__ __align__(16) ushort A2[8*APLANE];      // 8.3 KB
    __shared__ __align__(16) ushort B2[2*8*BPLANE];    // 41.2 KB (half0 reused as H2)
    __shared__ float sred[64][2];

    const int t = threadIdx.x;
    const int bid = blockIdx.x;
    const int local = (bid & 7) * 64 + (bid >> 3);   // 512 blocks, 8 XCD chunks of 64
    const int row0 = (local >> 1) * 64;
    const int cgp = local & 1;                        // col-group pair
    const int lane = t & 63;
    const int w = t >> 6;
    const int wr = w >> 1;
    const int wc = w & 1;
    const int l15 = lane & 15;
    const int lg = lane >> 4;       // 0..3

    const int arow = t >> 2;            // 0..63
    const int acol = (t & 3) * 16;

    ushort* aw0 = &A2[((t & 3) * 2    ) * APLANE + arow * 8];
    ushort* aw1 = &A2[((t & 3) * 2 + 1) * APLANE + arow * 8];

    const float* srcF = A + (long)(row0 + arow) * EE + acol;

#define BSRC(P) (Wbig + (long)((cgp*2 + ((P) >= 5 ? 1 : 0))*160 + ((P) % 5)*32 + (t >> 3)) * EE + (t & 7) * 8)
#define BDST(P) (&B2[((P) >= 5 ? 8*BPLANE : 0) + (t & 7) * BPLANE + (((P) % 5)*32 + (t >> 3)) * 8])
    const ushort *bs0 = BSRC(0), *bs1 = BSRC(1), *bs2 = BSRC(2), *bs3 = BSRC(3), *bs4 = BSRC(4);
    const ushort *bs5 = BSRC(5), *bs6 = BSRC(6), *bs7 = BSRC(7), *bs8 = BSRC(8), *bs9 = BSRC(9);
    ushort *bw0 = BDST(0), *bw1 = BDST(1), *bw2 = BDST(2), *bw3 = BDST(3), *bw4 = BDST(4);
    ushort *bw5 = BDST(5), *bw6 = BDST(6), *bw7 = BDST(7), *bw8 = BDST(8), *bw9 = BDST(9);
#undef BSRC
#undef BDST

    f32x4 raf0, raf1, raf2, raf3;
    f32x4 saf0, saf1, saf2, saf3;
    uint4 rb0, rb1, rb2, rb3, rb4, rb5, rb6, rb7, rb8, rb9;

    f32x4 acc[2][10];
#pragma unroll
    for (int m = 0; m < 2; ++m)
#pragma unroll
        for (int n = 0; n < 10; ++n) acc[m][n] = (f32x4){0.f, 0.f, 0.f, 0.f};

#define LOAD_A_R(K0)                                                           \
    do {                                                                       \
        raf0 = *(const f32x4*)(srcF + (K0));                                   \
        raf1 = *(const f32x4*)(srcF + (K0) + 4);                               \
        raf2 = *(const f32x4*)(srcF + (K0) + 8);                               \
        raf3 = *(const f32x4*)(srcF + (K0) + 12);                              \
    } while (0)
#define LOAD_A_S(K0)                                                           \
    do {                                                                       \
        saf0 = *(const f32x4*)(srcF + (K0));                                   \
        saf1 = *(const f32x4*)(srcF + (K0) + 4);                               \
        saf2 = *(const f32x4*)(srcF + (K0) + 8);                               \
        saf3 = *(const f32x4*)(srcF + (K0) + 12);                              \
    } while (0)
#define LOAD_B(K0)                                                             \
    do {                                                                       \
        rb0 = *(const uint4*)(bs0 + (K0)); rb1 = *(const uint4*)(bs1 + (K0));  \
        rb2 = *(const uint4*)(bs2 + (K0)); rb3 = *(const uint4*)(bs3 + (K0));  \
        rb4 = *(const uint4*)(bs4 + (K0)); rb5 = *(const uint4*)(bs5 + (K0));  \
        rb6 = *(const uint4*)(bs6 + (K0)); rb7 = *(const uint4*)(bs7 + (K0));  \
        rb8 = *(const uint4*)(bs8 + (K0)); rb9 = *(const uint4*)(bs9 + (K0));  \
    } while (0)
#define WRITE_A_R()                                                            \
    do {                                                                       \
        uint4 w0, w1;                                                          \
        w0.x = f2b2(raf0[0], raf0[1]); w0.y = f2b2(raf0[2], raf0[3]);          \
        w0.z = f2b2(raf1[0], raf1[1]); w0.w = f2b2(raf1[2], raf1[3]);          \
        w1.x = f2b2(raf2[0], raf2[1]); w1.y = f2b2(raf2[2], raf2[3]);          \
        w1.z = f2b2(raf3[0], raf3[1]); w1.w = f2b2(raf3[2], raf3[3]);          \
        *(uint4*)aw0 = w0; *(uint4*)aw1 = w1;                                  \
    } while (0)
#define WRITE_A_S()                                                            \
    do {                                                                       \
        uint4 w0, w1;                                                          \
        w0.x = f2b2(saf0[0], saf0[1]); w0.y = f2b2(saf0[2], saf0[3]);          \
        w0.z = f2b2(saf1[0], saf1[1]); w0.w = f2b2(saf1[2], saf1[3]);          \
        w1.x = f2b2(saf2[0], saf2[1]); w1.y = f2b2(saf2[2], saf2[3]);          \
        w1.z = f2b2(saf3[0], saf3[1]); w1.w = f2b2(saf3[2], saf3[3]);          \
        *(uint4*)aw0 = w0; *(uint4*)aw1 = w1;                                  \
    } while (0)
#define WRITE_B()                                                              \
    do {                                                                       \
        *(uint4*)bw0 = rb0; *(uint4*)bw1 = rb1; *(uint4*)bw2 = rb2;            \
        *(uint4*)bw3 = rb3; *(uint4*)bw4 = rb4; *(uint4*)bw5 = rb5;            \
        *(uint4*)bw6 = rb6; *(uint4*)bw7 = rb7; *(uint4*)bw8 = rb8;            \
        *(uint4*)bw9 = rb9;                                                    \
    } while (0)
#define MFMA_PHASE()                                                           \
    do {                                                                       \
        _Pragma("unroll")                                                      \
        for (int ks = 0; ks < 2; ++ks) {                                       \
            const int kg = ks * 4 + lg;                                        \
            short8 af2[2];                                                     \
            _Pragma("unroll")                                                  \
            for (int m = 0; m < 2; ++m)                                        \
                af2[m] = *(const short8*)&A2[kg * APLANE + (wr*32 + m*16 + l15) * 8]; \
            _Pragma("unroll")                                                  \
            for (int c = 0; c < 2; ++c) {                                      \
                _Pragma("unroll")                                              \
                for (int n = 0; n < 5; ++n) {                                  \
                    short8 bf = *(const short8*)&B2[c*8*BPLANE + kg * BPLANE + (wc*80 + n*16 + l15) * 8]; \
                    _Pragma("unroll")                                          \
                    for (int m = 0; m < 2; ++m)                                \
                        acc[m][c*5+n] = __builtin_amdgcn_mfma_f32_16x16x32_bf16(af2[m], bf, acc[m][c*5+n], 0, 0, 0); \
                }                                                              \
            }                                                                  \
        }                                                                      \
    } while (0)

    LOAD_A_R(0);
    LOAD_A_S(64);
    LOAD_B(0);
    for (int k0 = 0; k0 < EE; k0 += 128) {
        if (k0) __syncthreads();
        WRITE_A_R(); WRITE_B();
        __syncthreads();
        if (k0 + 128 < EE) LOAD_A_R(k0 + 128);
        LOAD_B(k0 + 64);
        MFMA_PHASE();
        __syncthreads();
        WRITE_A_S(); WRITE_B();
        __syncthreads();
        if (k0 + 192 < EE) LOAD_A_S(k0 + 192);
        if (k0 + 128 < EE) LOAD_B(k0 + 128);
        MFMA_PHASE();
    }
#undef LOAD_A_R
#undef LOAD_A_S
#undef LOAD_B
#undef WRITE_A_R
#undef WRITE_A_S
#undef WRITE_B
#undef MFMA_PHASE

    if (cgp == 0) {
        // ---- cg1 -> Pa (cols 0..159) ----
#pragma unroll
        for (int m = 0; m < 2; ++m) {
            int rbase = row0 + wr*32 + m*16 + lg * 4;
#pragma unroll
            for (int n = 0; n < 5; ++n) {
                int col = wc*80 + n*16 + l15;
#pragma unroll
                for (int r = 0; r < 4; ++r)
                    Pabc[(long)(rbase + r) * 480 + col] = f2b(acc[m][5+n][r]);
            }
        }
        // ---- cg0 -> fused attn layer-2 + score ----
        __syncthreads();
        ushort* H2 = B2;                 // h1 tile, fragment-major [20 granules][64 rows][8]
#pragma unroll
        for (int m = 0; m < 2; ++m) {
            int rloc = wr*32 + m*16 + lg*4;
#pragma unroll
            for (int n = 0; n < 5; ++n) {
                int col = wc*80 + n*16 + l15;
                float b = biases[col];
#pragma unroll
                for (int r = 0; r < 4; ++r) {
                    float v = acc[m][n][r] + b;
                    v = v > 0.f ? v : 0.f;
                    H2[((col >> 3) * 64 + rloc + r) * 8 + (col & 7)] = f2b(v);
                }
            }
        }
        __syncthreads();
        f32x4 acc2[2][5];
#pragma unroll
        for (int m = 0; m < 2; ++m)
#pragma unroll
            for (int n = 0; n < 5; ++n) acc2[m][n] = (f32x4){0.f, 0.f, 0.f, 0.f};
#pragma unroll
        for (int s = 0; s < 5; ++s) {
            const int kg = 4*s + lg;
            short8 af2[2];
#pragma unroll
            for (int m = 0; m < 2; ++m)
                af2[m] = *(const short8*)&H2[(kg*64 + wr*32 + m*16 + l15) * 8];
#pragma unroll
            for (int n = 0; n < 5; ++n) {
                int j = wc*80 + n*16 + l15;
                short8 bf = *(const short8*)(a_w2t + (long)j * KP2 + kg * 8);
#pragma unroll
                for (int m = 0; m < 2; ++m)
                    acc2[m][n] = __builtin_amdgcn_mfma_f32_16x16x32_bf16(af2[m], bf, acc2[m][n], 0, 0, 0);
            }
        }
        float p[2][4];
#pragma unroll
        for (int m = 0; m < 2; ++m)
#pragma unroll
            for (int r = 0; r < 4; ++r) p[m][r] = 0.f;
#pragma unroll
        for (int n = 0; n < 5; ++n) {
            int col = wc*80 + n*16 + l15;
            float b2v = biases[HP + col];
            float w3v = (col < HH) ? a_w3[col] : 0.f;
#pragma unroll
            for (int m = 0; m < 2; ++m)
#pragma unroll
                for (int r = 0; r < 4; ++r) {
                    float v = acc2[m][n][r] + b2v;
                    v = v > 0.f ? v : 0.f;
                    p[m][r] += v * w3v;
                }
        }
#pragma unroll
        for (int mask = 1; mask < 16; mask <<= 1)
#pragma unroll
            for (int m = 0; m < 2; ++m)
#pragma unroll
                for (int r = 0; r < 4; ++r)
                    p[m][r] += __shfl_xor(p[m][r], mask, 16);
        if (l15 == 0) {
#pragma unroll
            for (int m = 0; m < 2; ++m)
#pragma unroll
                for (int r = 0; r < 4; ++r)
                    sred[wr*32 + m*16 + lg*4 + r][wc] = p[m][r];
        }
        __syncthreads();
        if (t < 64) attns[row0 + t] = sred[t][0] + sred[t][1] + a_b3[0];
    } else {
        // ---- cg2 -> Pb (cols 160..319), cg3 -> Pc (cols 320..479) ----
#pragma unroll
        for (int m = 0; m < 2; ++m) {
            int rbase = row0 + wr*32 + m*16 + lg * 4;
#pragma unroll
            for (int n = 0; n < 5; ++n) {
                int col = wc*80 + n*16 + l15;
#pragma unroll
                for (int r = 0; r < 4; ++r) {
                    Pabc[(long)(rbase + r) * 480 + 160 + col] = f2b(acc[m][n][r]);
                    Pabc[(long)(rbase + r) * 480 + 320 + col] = f2b(acc[m][5+n][r]);
                }
            }
        }
    }
}

// ---------- span: out0 = [start_e|end_e|span_sum]; FUSED mention MLP -> score ----------
// Phase B computes h1m row in f32 (LDS, never hits HBM), then 150 threads each
// compute one layer-2 column (s_w2 read f32, coalesced across threads, L2-hot),
// relu * w3, wave-reduce -> mention score. Deletes the mention GEMM kernel.
__global__ __launch_bounds__(256) void span_kernel(
    const float* __restrict__ embeds, const float* __restrict__ attns,
    const int* __restrict__ starts, const int* __restrict__ lens,
    float* __restrict__ out,
    const ushort* __restrict__ Pabc, const float* __restrict__ biases2,
    const float* __restrict__ s_w2, const float* __restrict__ s_b2,
    const float* __restrict__ s_w3, const float* __restrict__ s_b3)
{
    __shared__ float at[32];
    __shared__ float h1lds[HP];
    __shared__ float wred[4];
    int bid = blockIdx.x;
    int swz = (bid & 7) * (NS / 8) + (bid >> 3);   // bijective (16000 % 8 == 0)
    int b = swz / SS, s = swz - b * SS;
    int t = threadIdx.x;
    int st = starts[b*SS + s];
    int len = lens[b*SS + s];       // inclusive span st..st+len, len+1 <= 30 rows
    int en = st + len;
    if (t < 30) at[t] = attns[b*TT + st + t];
    __syncthreads();
    // ---- phase A: span_embeds -> out (non-temporal stores) ----
    int e4 = t * 4;
    long ebase = ((long)(b*TT + st)) * EE + e4;
    long eend  = ((long)(b*TT + en)) * EE + e4;
    long obase = ((long)(b*SS + s)) * 3072 + e4;
    {
        f32x4 se = *(const f32x4*)(embeds + ebase);
        f32x4 ed = *(const f32x4*)(embeds + eend);
        float ax = 0.f, ay = 0.f, az = 0.f, aw = 0.f;
        for (int i = 0; i <= len; ++i) {
            float a = at[i];
            f32x4 v = *(const f32x4*)(embeds + ebase + (long)i * EE);
            ax += v.x * a; ay += v.y * a; az += v.z * a; aw += v.w * a;
        }
        f32x4 sm = {ax, ay, az, aw};
        __builtin_nontemporal_store(se, (f32x4*)(out + obase));
        __builtin_nontemporal_store(ed, (f32x4*)(out + obase + 1024));
        __builtin_nontemporal_store(sm, (f32x4*)(out + obase + 2048));
    }
    // ---- phase B: mention layer-1 row (f32, stays in LDS) ----
    long rowi = (long)(b*SS + s);
    if (t < HP) {
        float h1v = biases2[t]
                  + b2f(Pabc[((long)(b*TT + st)) * 480 + t])
                  + b2f(Pabc[((long)(b*TT + en)) * 480 + 160 + t]);
        const ushort* pc = Pabc + ((long)(b*TT + st)) * 480 + 320 + t;
        for (int i = 0; i <= len; ++i) h1v += at[i] * b2f(pc[(long)i * 480]);
        h1lds[t] = h1v > 0.f ? h1v : 0.f;
    }
    __syncthreads();
    // ---- phase C: layer-2 col t + relu*w3 ----
    float p = 0.f;
    if (t < HH) {
        float a0 = 0.f, a1 = 0.f, a2 = 0.f, a3 = 0.f;
        int k = 0;
        for (; k + 4 <= HH; k += 4) {
            a0 += h1lds[k    ] * s_w2[(k    ) * HH + t];
            a1 += h1lds[k + 1] * s_w2[(k + 1) * HH + t];
            a2 += h1lds[k + 2] * s_w2[(k + 2) * HH + t];
            a3 += h1lds[k + 3] * s_w2[(k + 3) * HH + t];
        }
        for (; k < HH; ++k) a0 += h1lds[k] * s_w2[k * HH + t];
        float h2 = s_b2[t] + ((a0 + a1) + (a2 + a3));
        h2 = h2 > 0.f ? h2 : 0.f;
        p = h2 * s_w3[t];
    }
#pragma unroll
    for (int mask = 1; mask < 64; mask <<= 1)
        p += __shfl_xor(p, mask, 64);
    if ((t & 63) == 0) wred[t >> 6] = p;
    __syncthreads();
    if (t == 0)
        out[SPAN_ELEMS + rowi] = wred[0] + wred[1] + wred[2] + wred[3] + s_b3[0];
}

extern "C" void kernel_launch(void* const* d_in, const int* in_sizes, int n_in,
                              void* d_out, int out_size, void* d_ws, size_t ws_size,
                              hipStream_t stream)
{
    const float* embeds = (const float*)d_in[0];
    const float* a_w1 = (const float*)d_in[1];  const float* a_b1 = (const float*)d_in[2];
    const float* a_w2 = (const float*)d_in[3];  const float* a_b2 = (const float*)d_in[4];
    const float* a_w3 = (const float*)d_in[5];  const float* a_b3 = (const float*)d_in[6];
    const float* s_w1 = (const float*)d_in[7];  const float* s_b1 = (const float*)d_in[8];
    const float* s_w2 = (const float*)d_in[9];  const float* s_b2 = (const float*)d_in[10];
    const float* s_w3 = (const float*)d_in[11]; const float* s_b3 = (const float*)d_in[12];
    const int* starts = (const int*)d_in[13];
    const int* lens   = (const int*)d_in[14];
    float* out = (float*)d_out;

    // workspace layout — ~17 MB
    char* ws = (char*)d_ws;
    ushort* Wbig  = (ushort*)ws;               ws += (size_t)NB*EE*2;        // 1.31 MB
    ushort* a_w2t = (ushort*)ws;               ws += (size_t)HP*KP2*2;       // 60 KB
    float*  biases = (float*)ws;               ws += (size_t)4*HP*4;         // 2.5 KB
    ushort* Pabc = (ushort*)ws;                ws += (size_t)NT*480*2;       // 15.7 MB
    float*  attns = (float*)ws;                ws += (size_t)NT*4;           // 64 KB

    prep_kernel<<<dim3(NB, 3), 256, 0, stream>>>(a_w1, s_w1, a_w2,
                                                 a_b1, a_b2, s_b1, s_b2,
                                                 Wbig, a_w2t, biases);
    // fused: layer-1 GEMM (h1 + Pabc, 2 cg/block) + attn layer-2 + attn score
    big_gemm_kernel<<<NT/64*2, 256, 0, stream>>>(embeds, Wbig, biases,
                                                 a_w2t, a_w3, a_b3, attns, Pabc);
    // spans: output 0 + FUSED full mention MLP -> scores (XCD-swizzled)
    span_kernel<<<NS, 256, 0, stream>>>(embeds, attns, starts, lens, out,
                                        Pabc, biases + 2*HP,
                                        s_w2, s_b2, s_w3, s_b3);
}

// Round 21
// 115.887 us; speedup vs baseline: 1.3973x; 1.3973x over previous
//
#include <hip/hip_runtime.h>
#include <hip/hip_bf16.h>

// ---------- problem constants ----------
#define BB 8
#define TT 2048
#define EE 1024
#define SS 2000
#define HH 150
#define HP 160     // padded hidden (GEMM N)
#define KP2 192    // padded K for layer-2 GEMMs
#define NB 640     // big-GEMM N: [a_w1 | s_w1a | s_w1b | s_w1c] -> 4 x 160
#define NT (BB*TT)     // 16384 tokens
#define NS (BB*SS)     // 16000 spans
#define SPAN_ELEMS ((long)NS*3072)

#define APLANE 520    // 64*8 + 8 ushorts
#define BPLANE 1288   // 160*8 + 8 ushorts

typedef __attribute__((ext_vector_type(8))) short short8;
typedef __attribute__((ext_vector_type(4))) float f32x4;
typedef __attribute__((ext_vector_type(4))) ushort u16x4;

__device__ __forceinline__ float b2f(ushort u) {
    union { uint i; float f; } v; v.i = ((uint)u) << 16; return v.f;
}
__device__ __forceinline__ ushort f2b(float f) {
    union { __hip_bfloat16 b; ushort u; } v; v.b = __float2bfloat16(f); return v.u;
}
__device__ __forceinline__ uint f2b2(float lo, float hi) {   // pack 2 bf16 into u32
    return (uint)f2b(lo) | ((uint)f2b(hi) << 16);
}

// ---------- weight prep (inputs verified f32; 640 thin blocks) ----------
__global__ void prep_kernel(const float* __restrict__ a_w1, const float* __restrict__ s_w1,
                            const float* __restrict__ a_w2, const float* __restrict__ s_w2,
                            const float* __restrict__ a_b1, const float* __restrict__ a_b2,
                            const float* __restrict__ s_b1, const float* __restrict__ s_b2,
                            ushort* __restrict__ Wbig,
                            ushort* __restrict__ a_w2t, ushort* __restrict__ s_w2t,
                            float* __restrict__ biases)
{
    int j = blockIdx.x;
    int which = blockIdx.y;
    int t = threadIdx.x;
    if (which == 0) {          // j in 0..639
        int p = j / 160, jj = j - p * 160;
        for (int k = t; k < EE; k += 256) {
            float v = 0.f;
            if (jj < HH)
                v = (p == 0) ? a_w1[(long)k * HH + jj]
                             : s_w1[((long)(p - 1) * EE + k) * HH + jj];
            Wbig[(long)j * EE + k] = f2b(v);
        }
    } else if (which == 1) {
        if (j < HP)
            for (int k = t; k < KP2; k += 256)
                a_w2t[j * KP2 + k] = (j < HH && k < HH) ? f2b(a_w2[(long)k * HH + j]) : (ushort)0;
    } else if (which == 2) {
        if (j < HP)
            for (int k = t; k < KP2; k += 256)
                s_w2t[j * KP2 + k] = (j < HH && k < HH) ? f2b(s_w2[(long)k * HH + j]) : (ushort)0;
    } else {
        if (j == 0 && t < HP) {
            biases[t]          = (t < HH) ? a_b1[t] : 0.f;
            biases[HP + t]     = (t < HH) ? a_b2[t] : 0.f;
            biases[2*HP + t]   = (t < HH) ? s_b1[t] : 0.f;
            biases[3*HP + t]   = (t < HH) ? s_b2[t] : 0.f;
        }
    }
}

// ---------- big token GEMM + fused attn MLP (round-16 structure, best known) ----------
// 2 col-groups per block (N=320): embeds A-tile fetched 2x total instead of 4x.
// A staged 2-deep (HBM latency); B staged 1-deep in LDS (Wbig L2-hot).
// pair0 (cgp==0): cg0 = attn h1 -> fused layer2+score; cg1 = Pa.
// pair1 (cgp==1): cg2 = Pb; cg3 = Pc.
__global__ __launch_bounds__(256, 2) void big_gemm_kernel(
    const float* __restrict__ A,
    const ushort* __restrict__ Wbig,
    const float* __restrict__ biases,
    const ushort* __restrict__ a_w2t,
    const float* __restrict__ a_w3, const float* __restrict__ a_b3,
    float* __restrict__ attns, ushort* __restrict__ Pabc)
{
    __shared__ __align__(16) ushort A2[8*APLANE];      // 8.3 KB
    __shared__ __align__(16) ushort B2[2*8*BPLANE];    // 41.2 KB (half0 reused as H2)
    __shared__ float sred[64][2];

    const int t = threadIdx.x;
    const int bid = blockIdx.x;
    const int local = (bid & 7) * 64 + (bid >> 3);   // 512 blocks, 8 XCD chunks of 64
    const int row0 = (local >> 1) * 64;
    const int cgp = local & 1;                        // col-group pair
    const int lane = t & 63;
    const int w = t >> 6;
    const int wr = w >> 1;
    const int wc = w & 1;
    const int l15 = lane & 15;
    const int lg = lane >> 4;       // 0..3

    const int arow = t >> 2;            // 0..63
    const int acol = (t & 3) * 16;

    ushort* aw0 = &A2[((t & 3) * 2    ) * APLANE + arow * 8];
    ushort* aw1 = &A2[((t & 3) * 2 + 1) * APLANE + arow * 8];

    const float* srcF = A + (long)(row0 + arow) * EE + acol;

    // B: 2560 granules / 256 threads = 10 per thread; p<5 -> cg half 0, p>=5 -> half 1
#define BSRC(P) (Wbig + (long)((cgp*2 + ((P) >= 5 ? 1 : 0))*160 + ((P) % 5)*32 + (t >> 3)) * EE + (t & 7) * 8)
#define BDST(P) (&B2[((P) >= 5 ? 8*BPLANE : 0) + (t & 7) * BPLANE + (((P) % 5)*32 + (t >> 3)) * 8])
    const ushort *bs0 = BSRC(0), *bs1 = BSRC(1), *bs2 = BSRC(2), *bs3 = BSRC(3), *bs4 = BSRC(4);
    const ushort *bs5 = BSRC(5), *bs6 = BSRC(6), *bs7 = BSRC(7), *bs8 = BSRC(8), *bs9 = BSRC(9);
    ushort *bw0 = BDST(0), *bw1 = BDST(1), *bw2 = BDST(2), *bw3 = BDST(3), *bw4 = BDST(4);
    ushort *bw5 = BDST(5), *bw6 = BDST(6), *bw7 = BDST(7), *bw8 = BDST(8), *bw9 = BDST(9);
#undef BSRC
#undef BDST

    // staging registers: A 2-deep, B 1-deep
    f32x4 raf0, raf1, raf2, raf3;
    f32x4 saf0, saf1, saf2, saf3;
    uint4 rb0, rb1, rb2, rb3, rb4, rb5, rb6, rb7, rb8, rb9;

    f32x4 acc[2][10];
#pragma unroll
    for (int m = 0; m < 2; ++m)
#pragma unroll
        for (int n = 0; n < 10; ++n) acc[m][n] = (f32x4){0.f, 0.f, 0.f, 0.f};

#define LOAD_A_R(K0)                                                           \
    do {                                                                       \
        raf0 = *(const f32x4*)(srcF + (K0));                                   \
        raf1 = *(const f32x4*)(srcF + (K0) + 4);                               \
        raf2 = *(const f32x4*)(srcF + (K0) + 8);                               \
        raf3 = *(const f32x4*)(srcF + (K0) + 12);                              \
    } while (0)
#define LOAD_A_S(K0)                                                           \
    do {                                                                       \
        saf0 = *(const f32x4*)(srcF + (K0));                                   \
        saf1 = *(const f32x4*)(srcF + (K0) + 4);                               \
        saf2 = *(const f32x4*)(srcF + (K0) + 8);                               \
        saf3 = *(const f32x4*)(srcF + (K0) + 12);                              \
    } while (0)
#define LOAD_B(K0)                                                             \
    do {                                                                       \
        rb0 = *(const uint4*)(bs0 + (K0)); rb1 = *(const uint4*)(bs1 + (K0));  \
        rb2 = *(const uint4*)(bs2 + (K0)); rb3 = *(const uint4*)(bs3 + (K0));  \
        rb4 = *(const uint4*)(bs4 + (K0)); rb5 = *(const uint4*)(bs5 + (K0));  \
        rb6 = *(const uint4*)(bs6 + (K0)); rb7 = *(const uint4*)(bs7 + (K0));  \
        rb8 = *(const uint4*)(bs8 + (K0)); rb9 = *(const uint4*)(bs9 + (K0));  \
    } while (0)
#define WRITE_A_R()                                                            \
    do {                                                                       \
        uint4 w0, w1;                                                          \
        w0.x = f2b2(raf0[0], raf0[1]); w0.y = f2b2(raf0[2], raf0[3]);          \
        w0.z = f2b2(raf1[0], raf1[1]); w0.w = f2b2(raf1[2], raf1[3]);          \
        w1.x = f2b2(raf2[0], raf2[1]); w1.y = f2b2(raf2[2], raf2[3]);          \
        w1.z = f2b2(raf3[0], raf3[1]); w1.w = f2b2(raf3[2], raf3[3]);          \
        *(uint4*)aw0 = w0; *(uint4*)aw1 = w1;                                  \
    } while (0)
#define WRITE_A_S()                                                            \
    do {                                                                       \
        uint4 w0, w1;                                                          \
        w0.x = f2b2(saf0[0], saf0[1]); w0.y = f2b2(saf0[2], saf0[3]);          \
        w0.z = f2b2(saf1[0], saf1[1]); w0.w = f2b2(saf1[2], saf1[3]);          \
        w1.x = f2b2(saf2[0], saf2[1]); w1.y = f2b2(saf2[2], saf2[3]);          \
        w1.z = f2b2(saf3[0], saf3[1]); w1.w = f2b2(saf3[2], saf3[3]);          \
        *(uint4*)aw0 = w0; *(uint4*)aw1 = w1;                                  \
    } while (0)
#define WRITE_B()                                                              \
    do {                                                                       \
        *(uint4*)bw0 = rb0; *(uint4*)bw1 = rb1; *(uint4*)bw2 = rb2;            \
        *(uint4*)bw3 = rb3; *(uint4*)bw4 = rb4; *(uint4*)bw5 = rb5;            \
        *(uint4*)bw6 = rb6; *(uint4*)bw7 = rb7; *(uint4*)bw8 = rb8;            \
        *(uint4*)bw9 = rb9;                                                    \
    } while (0)
#define MFMA_PHASE()                                                           \
    do {                                                                       \
        _Pragma("unroll")                                                      \
        for (int ks = 0; ks < 2; ++ks) {                                       \
            const int kg = ks * 4 + lg;                                        \
            short8 af2[2];                                                     \
            _Pragma("unroll")                                                  \
            for (int m = 0; m < 2; ++m)                                        \
                af2[m] = *(const short8*)&A2[kg * APLANE + (wr*32 + m*16 + l15) * 8]; \
            _Pragma("unroll")                                                  \
            for (int c = 0; c < 2; ++c) {                                      \
                _Pragma("unroll")                                              \
                for (int n = 0; n < 5; ++n) {                                  \
                    short8 bf = *(const short8*)&B2[c*8*BPLANE + kg * BPLANE + (wc*80 + n*16 + l15) * 8]; \
                    _Pragma("unroll")                                          \
                    for (int m = 0; m < 2; ++m)                                \
                        acc[m][c*5+n] = __builtin_amdgcn_mfma_f32_16x16x32_bf16(af2[m], bf, acc[m][c*5+n], 0, 0, 0); \
                }                                                              \
            }                                                                  \
        }                                                                      \
    } while (0)

    LOAD_A_R(0);
    LOAD_A_S(64);
    LOAD_B(0);
    for (int k0 = 0; k0 < EE; k0 += 128) {
        if (k0) __syncthreads();
        WRITE_A_R(); WRITE_B();
        __syncthreads();
        if (k0 + 128 < EE) LOAD_A_R(k0 + 128);
        LOAD_B(k0 + 64);
        MFMA_PHASE();
        __syncthreads();
        WRITE_A_S(); WRITE_B();
        __syncthreads();
        if (k0 + 192 < EE) LOAD_A_S(k0 + 192);
        if (k0 + 128 < EE) LOAD_B(k0 + 128);
        MFMA_PHASE();
    }
#undef LOAD_A_R
#undef LOAD_A_S
#undef LOAD_B
#undef WRITE_A_R
#undef WRITE_A_S
#undef WRITE_B
#undef MFMA_PHASE

    if (cgp == 0) {
        // ---- cg1 -> Pa (cols 0..159) ----
#pragma unroll
        for (int m = 0; m < 2; ++m) {
            int rbase = row0 + wr*32 + m*16 + lg * 4;
#pragma unroll
            for (int n = 0; n < 5; ++n) {
                int col = wc*80 + n*16 + l15;
#pragma unroll
                for (int r = 0; r < 4; ++r)
                    Pabc[(long)(rbase + r) * 480 + col] = f2b(acc[m][5+n][r]);
            }
        }
        // ---- cg0 -> fused attn layer-2 + score ----
        __syncthreads();
        ushort* H2 = B2;                 // h1 tile, fragment-major [20 granules][64 rows][8]
#pragma unroll
        for (int m = 0; m < 2; ++m) {
            int rloc = wr*32 + m*16 + lg*4;
#pragma unroll
            for (int n = 0; n < 5; ++n) {
                int col = wc*80 + n*16 + l15;
                float b = biases[col];
#pragma unroll
                for (int r = 0; r < 4; ++r) {
                    float v = acc[m][n][r] + b;
                    v = v > 0.f ? v : 0.f;
                    H2[((col >> 3) * 64 + rloc + r) * 8 + (col & 7)] = f2b(v);
                }
            }
        }
        __syncthreads();
        f32x4 acc2[2][5];
#pragma unroll
        for (int m = 0; m < 2; ++m)
#pragma unroll
            for (int n = 0; n < 5; ++n) acc2[m][n] = (f32x4){0.f, 0.f, 0.f, 0.f};
#pragma unroll
        for (int s = 0; s < 5; ++s) {
            const int kg = 4*s + lg;
            short8 af2[2];
#pragma unroll
            for (int m = 0; m < 2; ++m)
                af2[m] = *(const short8*)&H2[(kg*64 + wr*32 + m*16 + l15) * 8];
#pragma unroll
            for (int n = 0; n < 5; ++n) {
                int j = wc*80 + n*16 + l15;
                short8 bf = *(const short8*)(a_w2t + (long)j * KP2 + kg * 8);
#pragma unroll
                for (int m = 0; m < 2; ++m)
                    acc2[m][n] = __builtin_amdgcn_mfma_f32_16x16x32_bf16(af2[m], bf, acc2[m][n], 0, 0, 0);
            }
        }
        float p[2][4];
#pragma unroll
        for (int m = 0; m < 2; ++m)
#pragma unroll
            for (int r = 0; r < 4; ++r) p[m][r] = 0.f;
#pragma unroll
        for (int n = 0; n < 5; ++n) {
            int col = wc*80 + n*16 + l15;
            float b2v = biases[HP + col];
            float w3v = (col < HH) ? a_w3[col] : 0.f;
#pragma unroll
            for (int m = 0; m < 2; ++m)
#pragma unroll
                for (int r = 0; r < 4; ++r) {
                    float v = acc2[m][n][r] + b2v;
                    v = v > 0.f ? v : 0.f;
                    p[m][r] += v * w3v;
                }
        }
#pragma unroll
        for (int mask = 1; mask < 16; mask <<= 1)
#pragma unroll
            for (int m = 0; m < 2; ++m)
#pragma unroll
                for (int r = 0; r < 4; ++r)
                    p[m][r] += __shfl_xor(p[m][r], mask, 16);
        if (l15 == 0) {
#pragma unroll
            for (int m = 0; m < 2; ++m)
#pragma unroll
                for (int r = 0; r < 4; ++r)
                    sred[wr*32 + m*16 + lg*4 + r][wc] = p[m][r];
        }
        __syncthreads();
        if (t < 64) attns[row0 + t] = sred[t][0] + sred[t][1] + a_b3[0];
    } else {
        // ---- cg2 -> Pb (cols 160..319), cg3 -> Pc (cols 320..479) ----
#pragma unroll
        for (int m = 0; m < 2; ++m) {
            int rbase = row0 + wr*32 + m*16 + lg * 4;
#pragma unroll
            for (int n = 0; n < 5; ++n) {
                int col = wc*80 + n*16 + l15;
#pragma unroll
                for (int r = 0; r < 4; ++r) {
                    Pabc[(long)(rbase + r) * 480 + 160 + col] = f2b(acc[m][n][r]);
                    Pabc[(long)(rbase + r) * 480 + 320 + col] = f2b(acc[m][5+n][r]);
                }
            }
        }
    }
}

// ---------- fused layer-2 GEMM + score dot (mention path) ----------
__global__ __launch_bounds__(256) void gemm_relu_dot_kernel(
    const ushort* __restrict__ A,
    const ushort* __restrict__ Wt,
    const float* __restrict__ bias,
    const float* __restrict__ w3, const float* __restrict__ b3,
    float* __restrict__ outAll)
{
    __shared__ __align__(16) ushort A2[8*64*8];
    __shared__ __align__(16) ushort B2[8*160*8];
    __shared__ float w3lds[HP];
    __shared__ float red[64][2];

    const int t = threadIdx.x;
    const int row0 = blockIdx.x * 64;
    const int lane = t & 63;
    const int w = t >> 6;
    const int wr = w >> 1;
    const int wc = w & 1;
    const int l15 = lane & 15;
    const int kb = (lane >> 4) * 8;

    if (t < HP) w3lds[t] = (t < HH) ? w3[t] : 0.f;

    f32x4 acc[2][5];
#pragma unroll
    for (int m = 0; m < 2; ++m)
#pragma unroll
        for (int n = 0; n < 5; ++n) acc[m][n] = (f32x4){0.f, 0.f, 0.f, 0.f};

    const int arow = t >> 2;
    const int ag0 = (t & 3) * 2;

    for (int k0 = 0; k0 < KP2; k0 += 64) {
        {
            const ushort* src = A + (long)(row0 + arow) * KP2 + k0 + ag0 * 8;
            *(uint4*)&A2[((ag0    ) * 64 + arow) * 8] = *(const uint4*)(src);
            *(uint4*)&A2[((ag0 + 1) * 64 + arow) * 8] = *(const uint4*)(src + 8);
        }
#pragma unroll
        for (int p = 0; p < 5; ++p) {
            int gg = p * 256 + t;
            int br = gg >> 3;
            int bg = gg & 7;
            uint4 v = *(const uint4*)(Wt + (long)br * KP2 + k0 + bg * 8);
            *(uint4*)&B2[(bg * 160 + br) * 8] = v;
        }
        __syncthreads();
#pragma unroll
        for (int ks = 0; ks < 64; ks += 32) {
            const int kg = (ks + kb) >> 3;
            short8 af[2];
#pragma unroll
            for (int m = 0; m < 2; ++m)
                af[m] = *(const short8*)&A2[(kg * 64 + wr*32 + m*16 + l15) * 8];
#pragma unroll
            for (int n = 0; n < 5; ++n) {
                short8 bf = *(const short8*)&B2[(kg * 160 + wc*80 + n*16 + l15) * 8];
#pragma unroll
                for (int m = 0; m < 2; ++m)
                    acc[m][n] = __builtin_amdgcn_mfma_f32_16x16x32_bf16(af[m], bf, acc[m][n], 0, 0, 0);
            }
        }
        __syncthreads();
    }
    float w3c[5];
    float bc[5];
#pragma unroll
    for (int n = 0; n < 5; ++n) {
        int col = wc*80 + n*16 + l15;
        w3c[n] = w3lds[col];
        bc[n] = bias[col];
    }
    float p[2][4];
#pragma unroll
    for (int m = 0; m < 2; ++m)
#pragma unroll
        for (int r = 0; r < 4; ++r) {
            float s = 0.f;
#pragma unroll
            for (int n = 0; n < 5; ++n) {
                float v = acc[m][n][r] + bc[n];
                v = v > 0.f ? v : 0.f;
                s += v * w3c[n];
            }
            p[m][r] = s;
        }
#pragma unroll
    for (int mask = 1; mask < 16; mask <<= 1)
#pragma unroll
        for (int m = 0; m < 2; ++m)
#pragma unroll
            for (int r = 0; r < 4; ++r)
                p[m][r] += __shfl_xor(p[m][r], mask, 16);
    if (l15 == 0) {
        int g = lane >> 4;
#pragma unroll
        for (int m = 0; m < 2; ++m)
#pragma unroll
            for (int r = 0; r < 4; ++r)
                red[wr*32 + m*16 + g*4 + r][wc] = p[m][r];
    }
    __syncthreads();
    if (t < 64) {
        int row = row0 + t;
        outAll[SPAN_ELEMS + row] = red[t][0] + red[t][1] + b3[0];
    }
}

// ---------- span: out0 = [start_e|end_e|span_sum]; h1m = relu(Pa+Pb+Σa·Pc+b) ----------
__global__ __launch_bounds__(256) void span_kernel(
    const float* __restrict__ embeds, const float* __restrict__ attns,
    const int* __restrict__ starts, const int* __restrict__ lens,
    float* __restrict__ out,
    const ushort* __restrict__ Pabc, const float* __restrict__ biases2,
    ushort* __restrict__ h1m)
{
    __shared__ float at[32];
    int bid = blockIdx.x;
    int swz = (bid & 7) * (NS / 8) + (bid >> 3);   // bijective (16000 % 8 == 0)
    int b = swz / SS, s = swz - b * SS;
    int t = threadIdx.x;
    int st = starts[b*SS + s];
    int len = lens[b*SS + s];       // inclusive span st..st+len, len+1 <= 30 rows
    int en = st + len;
    if (t < 30) at[t] = attns[b*TT + st + t];
    __syncthreads();
    int e4 = t * 4;
    long ebase = ((long)(b*TT + st)) * EE + e4;
    long eend  = ((long)(b*TT + en)) * EE + e4;
    long obase = ((long)(b*SS + s)) * 3072 + e4;
    {
        f32x4 se = *(const f32x4*)(embeds + ebase);
        f32x4 ed = *(const f32x4*)(embeds + eend);
        float ax = 0.f, ay = 0.f, az = 0.f, aw = 0.f;
        for (int i = 0; i <= len; ++i) {
            float a = at[i];
            f32x4 v = *(const f32x4*)(embeds + ebase + (long)i * EE);
            ax += v.x * a; ay += v.y * a; az += v.z * a; aw += v.w * a;
        }
        f32x4 sm = {ax, ay, az, aw};
        __builtin_nontemporal_store(se, (f32x4*)(out + obase));
        __builtin_nontemporal_store(ed, (f32x4*)(out + obase + 1024));
        __builtin_nontemporal_store(sm, (f32x4*)(out + obase + 2048));
    }
    long rowi = (long)(b*SS + s);
    if (t < HP) {
        float acc = biases2[t]
                  + b2f(Pabc[((long)(b*TT + st)) * 480 + t])
                  + b2f(Pabc[((long)(b*TT + en)) * 480 + 160 + t]);
        const ushort* pc = Pabc + ((long)(b*TT + st)) * 480 + 320 + t;
        for (int i = 0; i <= len; ++i) acc += at[i] * b2f(pc[(long)i * 480]);
        acc = acc > 0.f ? acc : 0.f;
        h1m[rowi * KP2 + t] = f2b(acc);
    } else if (t < KP2) {
        h1m[rowi * KP2 + t] = 0;
    }
}

extern "C" void kernel_launch(void* const* d_in, const int* in_sizes, int n_in,
                              void* d_out, int out_size, void* d_ws, size_t ws_size,
                              hipStream_t stream)
{
    const float* embeds = (const float*)d_in[0];
    const float* a_w1 = (const float*)d_in[1];  const float* a_b1 = (const float*)d_in[2];
    const float* a_w2 = (const float*)d_in[3];  const float* a_b2 = (const float*)d_in[4];
    const float* a_w3 = (const float*)d_in[5];  const float* a_b3 = (const float*)d_in[6];
    const float* s_w1 = (const float*)d_in[7];  const float* s_b1 = (const float*)d_in[8];
    const float* s_w2 = (const float*)d_in[9];  const float* s_b2 = (const float*)d_in[10];
    const float* s_w3 = (const float*)d_in[11]; const float* s_b3 = (const float*)d_in[12];
    const int* starts = (const int*)d_in[13];
    const int* lens   = (const int*)d_in[14];
    float* out = (float*)d_out;

    // workspace layout — ~24 MB
    char* ws = (char*)d_ws;
    ushort* Wbig  = (ushort*)ws;               ws += (size_t)NB*EE*2;        // 1.31 MB
    ushort* a_w2t = (ushort*)ws;               ws += (size_t)HP*KP2*2;       // 60 KB
    ushort* s_w2t = (ushort*)ws;               ws += (size_t)HP*KP2*2;       // 60 KB
    float*  biases = (float*)ws;               ws += (size_t)4*HP*4;         // 2.5 KB
    ushort* Pabc = (ushort*)ws;                ws += (size_t)NT*480*2;       // 15.7 MB
    float*  attns = (float*)ws;                ws += (size_t)NT*4;           // 64 KB
    ushort* h1m  = (ushort*)ws;                ws += (size_t)NS*KP2*2;       // 6.1 MB

    prep_kernel<<<dim3(NB, 4), 256, 0, stream>>>(a_w1, s_w1, a_w2, s_w2,
                                                 a_b1, a_b2, s_b1, s_b2,
                                                 Wbig, a_w2t, s_w2t, biases);
    // fused: layer-1 GEMM (h1 + Pabc, 2 cg/block) + attn layer-2 + attn score
    big_gemm_kernel<<<NT/64*2, 256, 0, stream>>>(embeds, Wbig, biases,
                                                 a_w2t, a_w3, a_b3, attns, Pabc);
    // spans: output 0 + mention h1 via linearity (XCD-swizzled)
    span_kernel<<<NS, 256, 0, stream>>>(embeds, attns, starts, lens, out,
                                        Pabc, biases + 2*HP, h1m);
    // mention layer-2 + score (fused)
    gemm_relu_dot_kernel<<<NS/64, 256, 0, stream>>>(h1m, s_w2t, biases + 3*HP,
                                                    s_w3, s_b3, out);
}